// Round 2
// baseline (262.604 us; speedup 1.0000x reference)
//
#include <hip/hip_runtime.h>
#include <hip/hip_bf16.h>
#include <math.h>

#define C 8
#define K 128
#define S 64
#define L 2048
#define NB 64
#define W (L - S + 1)   // 1985
#define TW 128
#define NTW 16
#define XCS 208         // xcop stride shorts: 104 dw = 8 banks mod 32 -> conflict-free b128
#define XFS 200         // fp32 x scratch stride (192 data + 8 zero pad)

typedef __attribute__((ext_vector_type(8))) short bf16x8;
typedef __attribute__((ext_vector_type(4))) float f32x4;

__device__ __forceinline__ unsigned short f2bf(float f) {
  unsigned int u = __float_as_uint(f);
  u += 0x7FFFu + ((u >> 16) & 1u);   // RNE
  return (unsigned short)(u >> 16);
}

// packed f32x2 -> bf16x2 (v_cvt_pk_bf16_f32 on gfx950)
__device__ __forceinline__ unsigned int pkbf(float a, float b) {
  __hip_bfloat162 h = __float22bfloat162_rn(make_float2(a, b));
  return *reinterpret_cast<unsigned int*>(&h);
}

// prep: z-normalize shapelets -> bf16 * (-2), B-fragment order grouped by
// CHANNEL (16 KB contiguous per c, both 64k halves inside); init out to +inf.
// sum(z^2) == S == 64 exactly (population z-norm) -> no per-k sqs needed.
__global__ __launch_bounds__(256) void prep_kernel(const float* __restrict__ sh,
                                                   unsigned short* __restrict__ shzB,
                                                   float* __restrict__ out) {
  int tid = blockIdx.x * 256 + threadIdx.x;
  if (tid < NB * K) out[tid] = __int_as_float(0x7F800000);
  int gid = blockIdx.x * 4 + (threadIdx.x >> 6);  // c*K + k
  int lane = threadIdx.x & 63;                    // = s
  float v = sh[(size_t)gid * S + lane];
  float s1 = v, s2 = v * v;
#pragma unroll
  for (int off = 32; off > 0; off >>= 1) {
    s1 += __shfl_down(s1, off);
    s2 += __shfl_down(s2, off);
  }
  s1 = __shfl(s1, 0);
  s2 = __shfl(s2, 0);
  float mu = s1 * (1.0f / S);
  float sd = sqrtf(fmaxf(s2 * (1.0f / S) - mu * mu, 0.0f));
  float z = (v - mu) / sd;
  int c = gid >> 7, k = gid & (K - 1), s = lane;
  // layout: [c][k>>6][((k>>4)&3)*2 + (s>>5)][lane'=((s>>3)&3)*16+(k&15)][s&7]
  int idx = c * 8192 + (k >> 6) * 4096 + ((((k >> 4) & 3) * 2) + (s >> 5)) * 512 +
            ((((s >> 3) & 3) * 16 + (k & 15)) * 8) + (s & 7);
  shzB[idx] = f2bf(-2.0f * z);   // bake the -2 of d2 = (sqx + 64) - 2*cross
}

// main: block = 128w x 128k, 256 threads = 4 waves, wave tile 64w x 64k.
// B is NOT staged in LDS at all: 128 KB shzB is L1/L2-resident, and each wave's
// B fragments are contiguous in the prep layout -> 8 coalesced global
// dwordx4 loads per channel, double-buffered one channel ahead in registers.
// This deletes bbuf (LDS 63.5 -> 36.5 KB), all gll16 LDS-DMA writes, all B
// ds_reads, and EVERY main-loop barrier (nothing cooperative left in the loop)
// -> waves free-run, so the VALU (sqrt epilogue) and LDS (A/sqx reads) pipes
// overlap across resident waves instead of serializing in lockstep.
// Main-loop LDS per wave-channel: 8 A b128 + 4 sqx b128 = 12 (was 20 + DMA).
// Arithmetic order per output element is bit-identical to the previous kernel.
__global__ __launch_bounds__(256, 3) void main_kernel(const float* __restrict__ x,
                                                      const unsigned short* __restrict__ shzB,
                                                      int* __restrict__ out) {
  __shared__ __align__(16) unsigned short xcop[C][8][XCS]; // 26 KB: 8 shifted copies
  __shared__ __align__(16) float sqx[C][TW];               // 4 KB (pre-biased +64)
  __shared__ __align__(16) float xf[C][XFS];               // 6.4 KB fp32 x scratch

  const int t = threadIdx.x;
  const int lane = t & 63;
  const int wave = t >> 6;     // 0..3
  const int wgrp = wave & 1;   // w-offset 64
  const int kgrp = wave >> 1;  // 0..1 : k-offset 64*kgrp
  const int col = lane & 15;
  const int quad = lane >> 4;
  const int n = blockIdx.y;
  const int w0 = blockIdx.x * TW;
  const float* xn = x + (size_t)n * C * L;
  // this wave's B-fragment stream: 8 x 1KB contiguous chunks per channel
  const unsigned short* bw = shzB + kgrp * 4096 + lane * 8;

  // ---- issue B[c=0] register loads immediately; they land during staging ----
  bf16x8 B[2][8];
#pragma unroll
  for (int i = 0; i < 8; ++i)
    B[0][i] = *(const bf16x8*)(bw + i * 512);

  // ---- stage fp32 x segment into xf (2 ch/wave, float4/lane) ----
  float* xfp = &xf[0][0];
#pragma unroll
  for (int cc = 0; cc < 2; ++cc) {
    const int c = wave * 2 + cc;
    const int e = lane * 4;
    float4 v; v.x = v.y = v.z = v.w = 0.0f;
    if (lane < 48) {
      int g = w0 + e;
      if (g + 3 < L) {
        v = *(const float4*)(xn + c * L + g);
      } else {  // last w-tile tail; feeds masked windows only
        v.x = (g + 0 < L) ? xn[c * L + g + 0] : 0.0f;
        v.y = (g + 1 < L) ? xn[c * L + g + 1] : 0.0f;
        v.z = (g + 2 < L) ? xn[c * L + g + 2] : 0.0f;
        v.w = (g + 3 < L) ? xn[c * L + g + 3] : 0.0f;
      }
    }
    if (lane < 50) *(float4*)&xfp[c * XFS + e] = v;   // lanes 48,49 zero-pad tail
  }
  __syncthreads();

  // ---- build 8 shifted bf16 copies (2 ch/wave; r=lane>>3; 12 dwords/lane/ch) ----
#pragma unroll
  for (int cc = 0; cc < 2; ++cc) {
    const int cb = wave * 2 + cc;
    const int rb = lane >> 3;         // 0..7
    const int c8 = lane & 7;
    const float* xr = xfp + cb * XFS;
#pragma unroll
    for (int j = 0; j < 12; ++j) {
      int i = (c8 + j * 8) * 2;       // 0..190 even
      *(unsigned int*)&xcop[cb][rb][i] = pkbf(xr[i + rb], xr[i + rb + 1]);
    }
  }
  // ---- sliding-window fp32 sqx (+64 bias = sum(z^2)): 2 ch/wave, 2 w/lane ----
#pragma unroll
  for (int cc = 0; cc < 2; ++cc) {
    const int c = wave * 2 + cc, wl = lane * 2;
    const float* xr = xfp + c * XFS;
    float p0 = 0.f, p1 = 0.f, p2 = 0.f, p3 = 0.f;
#pragma unroll
    for (int si = 0; si < S; si += 4) {
      float v0 = xr[wl + si], v1 = xr[wl + si + 1], v2 = xr[wl + si + 2], v3 = xr[wl + si + 3];
      p0 = fmaf(v0, v0, p0); p1 = fmaf(v1, v1, p1);
      p2 = fmaf(v2, v2, p2); p3 = fmaf(v3, v3, p3);
    }
    float s0 = 64.0f + (p0 + p1) + (p2 + p3);
    sqx[c][wl] = s0;
    float a = xr[wl + S], b = xr[wl];
    sqx[c][wl + 1] = s0 + a * a - b * b;
  }
  __syncthreads();  // xcop + sqx ready; NO barriers after this point

  const f32x4 z4 = {0.0f, 0.0f, 0.0f, 0.0f};
  f32x4 dsum[4][4];   // [ktile][wtile]
#pragma unroll
  for (int kt = 0; kt < 4; ++kt)
#pragma unroll
    for (int wt = 0; wt < 4; ++wt) dsum[kt][wt] = z4;

  const int r8 = col & 7;
  const int abase = wgrp * 64 + (col - r8) + quad * 8;  // multiple of 8 -> b128 aligned

#pragma unroll
  for (int c = 0; c < C; ++c) {
    // prefetch next channel's B into the other register buffer; the entire
    // compute region below (~600+ cycles) covers the L1/L2 latency
    if (c + 1 < C) {
#pragma unroll
      for (int i = 0; i < 8; ++i)
        B[(c + 1) & 1][i] = *(const bf16x8*)(bw + (c + 1) * 8192 + i * 512);
    }

    const unsigned short* xc = &xcop[c][r8][0];
#pragma unroll
    for (int wt = 0; wt < 4; ++wt) {
      // acc init = sqx (broadcast read, shared across the 4 k-tiles)
      f32x4 ai = *(const f32x4*)&sqx[c][wgrp * 64 + wt * 16 + quad * 4];
      // A fragments read ONCE, feed 4 k-tiles
      bf16x8 x0 = *(const bf16x8*)(xc + abase + wt * 16);
      bf16x8 x1 = *(const bf16x8*)(xc + abase + wt * 16 + 32);
      f32x4 a0 = __builtin_amdgcn_mfma_f32_16x16x32_bf16(x0, B[c & 1][0], ai, 0, 0, 0);
      f32x4 a1 = __builtin_amdgcn_mfma_f32_16x16x32_bf16(x0, B[c & 1][2], ai, 0, 0, 0);
      f32x4 a2 = __builtin_amdgcn_mfma_f32_16x16x32_bf16(x0, B[c & 1][4], ai, 0, 0, 0);
      f32x4 a3 = __builtin_amdgcn_mfma_f32_16x16x32_bf16(x0, B[c & 1][6], ai, 0, 0, 0);
      a0 = __builtin_amdgcn_mfma_f32_16x16x32_bf16(x1, B[c & 1][1], a0, 0, 0, 0);
      a1 = __builtin_amdgcn_mfma_f32_16x16x32_bf16(x1, B[c & 1][3], a1, 0, 0, 0);
      a2 = __builtin_amdgcn_mfma_f32_16x16x32_bf16(x1, B[c & 1][5], a2, 0, 0, 0);
      a3 = __builtin_amdgcn_mfma_f32_16x16x32_bf16(x1, B[c & 1][7], a3, 0, 0, 0);
#pragma unroll
      for (int i = 0; i < 4; ++i) {
        dsum[0][wt][i] += __builtin_amdgcn_sqrtf(fmaxf(a0[i], 0.0f));
        dsum[1][wt][i] += __builtin_amdgcn_sqrtf(fmaxf(a1[i], 0.0f));
        dsum[2][wt][i] += __builtin_amdgcn_sqrtf(fmaxf(a2[i], 0.0f));
        dsum[3][wt][i] += __builtin_amdgcn_sqrtf(fmaxf(a3[i], 0.0f));
      }
    }
  }

  // min over w (regs -> quad shuffles), one atomicMin per (k-tile, lane col)
  const float INF = __int_as_float(0x7F800000);
  const int wbase = w0 + wgrp * 64;
#pragma unroll
  for (int kt = 0; kt < 4; ++kt) {
    float mv = INF;
#pragma unroll
    for (int wt = 0; wt < 4; ++wt)
#pragma unroll
      for (int i = 0; i < 4; ++i) {
        int w = wbase + wt * 16 + quad * 4 + i;
        mv = (w < W) ? fminf(mv, dsum[kt][wt][i]) : mv;
      }
    mv = fminf(mv, __shfl_xor(mv, 16));
    mv = fminf(mv, __shfl_xor(mv, 32));
    if (quad == 0)
      atomicMin(&out[n * K + kgrp * 64 + kt * 16 + col], __float_as_int(mv));
  }
}

extern "C" void kernel_launch(void* const* d_in, const int* in_sizes, int n_in,
                              void* d_out, int out_size, void* d_ws, size_t ws_size,
                              hipStream_t stream) {
  const float* x = (const float*)d_in[0];    // (64, 8, 2048) fp32
  const float* sh = (const float*)d_in[1];   // (8, 128, 64) fp32
  float* out = (float*)d_out;                // (64, 1, 128) fp32
  unsigned short* shzB = (unsigned short*)d_ws;  // 128 KB bf16 B-frag layout (scaled -2)

  prep_kernel<<<256, 256, 0, stream>>>(sh, shzB, out);
  main_kernel<<<dim3(NTW, NB), 256, 0, stream>>>(x, shzB, (int*)out);
}

// Round 4
// 87.921 us; speedup vs baseline: 2.9868x; 2.9868x over previous
//
#include <hip/hip_runtime.h>
#include <hip/hip_bf16.h>
#include <math.h>

#define C 8
#define K 128
#define S 64
#define L 2048
#define NB 64
#define W (L - S + 1)   // 1985
#define TW 128
#define NTW 16
#define XCS 208         // xcop stride shorts: 104 dw = 8 banks mod 32 -> conflict-free b128
#define XFS 200         // fp32 x scratch stride (192 data + 8 zero pad)

typedef __attribute__((ext_vector_type(8))) short bf16x8;
typedef __attribute__((ext_vector_type(4))) float f32x4;

__device__ __forceinline__ unsigned short f2bf(float f) {
  unsigned int u = __float_as_uint(f);
  u += 0x7FFFu + ((u >> 16) & 1u);   // RNE
  return (unsigned short)(u >> 16);
}

// packed f32x2 -> bf16x2 (v_cvt_pk_bf16_f32 on gfx950)
__device__ __forceinline__ unsigned int pkbf(float a, float b) {
  __hip_bfloat162 h = __float22bfloat162_rn(make_float2(a, b));
  return *reinterpret_cast<unsigned int*>(&h);
}

// prep: z-normalize shapelets -> bf16 * (-2), B-fragment order grouped by
// CHANNEL (16 KB contiguous per c, both 64k halves inside); init out to +inf.
// sum(z^2) == S == 64 exactly (population z-norm) -> no per-k sqs needed.
__global__ __launch_bounds__(256) void prep_kernel(const float* __restrict__ sh,
                                                   unsigned short* __restrict__ shzB,
                                                   float* __restrict__ out) {
  int tid = blockIdx.x * 256 + threadIdx.x;
  if (tid < NB * K) out[tid] = __int_as_float(0x7F800000);
  int gid = blockIdx.x * 4 + (threadIdx.x >> 6);  // c*K + k
  int lane = threadIdx.x & 63;                    // = s
  float v = sh[(size_t)gid * S + lane];
  float s1 = v, s2 = v * v;
#pragma unroll
  for (int off = 32; off > 0; off >>= 1) {
    s1 += __shfl_down(s1, off);
    s2 += __shfl_down(s2, off);
  }
  s1 = __shfl(s1, 0);
  s2 = __shfl(s2, 0);
  float mu = s1 * (1.0f / S);
  float sd = sqrtf(fmaxf(s2 * (1.0f / S) - mu * mu, 0.0f));
  float z = (v - mu) / sd;
  int c = gid >> 7, k = gid & (K - 1), s = lane;
  // layout: [c][k>>6][((k>>4)&3)*2 + (s>>5)][lane'=((s>>3)&3)*16+(k&15)][s&7]
  int idx = c * 8192 + (k >> 6) * 4096 + ((((k >> 4) & 3) * 2) + (s >> 5)) * 512 +
            ((((s >> 3) & 3) * 16 + (k & 15)) * 8) + (s & 7);
  shzB[idx] = f2bf(-2.0f * z);   // bake the -2 of d2 = (sqx + 64) - 2*cross
}

// main: block = 128w x 128k, 256 threads = 4 waves, wave tile 64w x 64k.
// Barrier-free main loop: B comes straight from global (128 KB shzB is
// L1/L2-resident; each wave's fragments are 8 coalesced dwordx4 per channel)
// into a SINGLE named register buffer declared inside the loop body — every
// index is compile-time static regardless of unroll decisions (R2 lesson:
// a runtime-indexed 2-deep buffer went to local memory, 396 MB of traffic).
// R3 lesson: `#pragma unroll 2` on this loop produced a post-timing
// nondeterminism — REMOVED; the plain loop (any unroll factor keeps static
// indices) is what R2 already ran deterministically.
// LDS 37.1 KB -> 4 blocks/CU; launch_bounds(256,3) caps VGPR so >=12 waves/CU
// stay resident. No __syncthreads in the loop -> waves free-run and the VALU
// (sqrt epilogue), LDS (A/sqx reads), VMEM (B loads) and MFMA pipes overlap
// across resident waves. Arithmetic order per output element is bit-identical
// to R0/R1/R2.
__global__ __launch_bounds__(256, 3) void main_kernel(const float* __restrict__ x,
                                                      const unsigned short* __restrict__ shzB,
                                                      int* __restrict__ out) {
  __shared__ __align__(16) unsigned short xcop[C][8][XCS]; // 26 KB: 8 shifted copies
  __shared__ __align__(16) float sqx[C][TW];               // 4 KB (pre-biased +64)
  __shared__ __align__(16) float xf[C][XFS];               // 6.4 KB fp32 x scratch

  const int t = threadIdx.x;
  const int lane = t & 63;
  const int wave = t >> 6;     // 0..3
  const int wgrp = wave & 1;   // w-offset 64
  const int kgrp = wave >> 1;  // 0..1 : k-offset 64*kgrp
  const int col = lane & 15;
  const int quad = lane >> 4;
  const int n = blockIdx.y;
  const int w0 = blockIdx.x * TW;
  const float* xn = x + (size_t)n * C * L;
  // this wave's B-fragment stream: 8 x 1KB contiguous chunks per channel
  const unsigned short* bw = shzB + kgrp * 4096 + lane * 8;

  // ---- stage fp32 x segment into xf (2 ch/wave, float4/lane) ----
  float* xfp = &xf[0][0];
#pragma unroll
  for (int cc = 0; cc < 2; ++cc) {
    const int c = wave * 2 + cc;
    const int e = lane * 4;
    float4 v; v.x = v.y = v.z = v.w = 0.0f;
    if (lane < 48) {
      int g = w0 + e;
      if (g + 3 < L) {
        v = *(const float4*)(xn + c * L + g);
      } else {  // last w-tile tail; feeds masked windows only
        v.x = (g + 0 < L) ? xn[c * L + g + 0] : 0.0f;
        v.y = (g + 1 < L) ? xn[c * L + g + 1] : 0.0f;
        v.z = (g + 2 < L) ? xn[c * L + g + 2] : 0.0f;
        v.w = (g + 3 < L) ? xn[c * L + g + 3] : 0.0f;
      }
    }
    if (lane < 50) *(float4*)&xfp[c * XFS + e] = v;   // lanes 48,49 zero-pad tail
  }
  __syncthreads();

  // ---- build 8 shifted bf16 copies (2 ch/wave; r=lane>>3; 12 dwords/lane/ch) ----
#pragma unroll
  for (int cc = 0; cc < 2; ++cc) {
    const int cb = wave * 2 + cc;
    const int rb = lane >> 3;         // 0..7
    const int c8 = lane & 7;
    const float* xr = xfp + cb * XFS;
#pragma unroll
    for (int j = 0; j < 12; ++j) {
      int i = (c8 + j * 8) * 2;       // 0..190 even
      *(unsigned int*)&xcop[cb][rb][i] = pkbf(xr[i + rb], xr[i + rb + 1]);
    }
  }
  // ---- sliding-window fp32 sqx (+64 bias = sum(z^2)): 2 ch/wave, 2 w/lane ----
#pragma unroll
  for (int cc = 0; cc < 2; ++cc) {
    const int c = wave * 2 + cc, wl = lane * 2;
    const float* xr = xfp + c * XFS;
    float p0 = 0.f, p1 = 0.f, p2 = 0.f, p3 = 0.f;
#pragma unroll
    for (int si = 0; si < S; si += 4) {
      float v0 = xr[wl + si], v1 = xr[wl + si + 1], v2 = xr[wl + si + 2], v3 = xr[wl + si + 3];
      p0 = fmaf(v0, v0, p0); p1 = fmaf(v1, v1, p1);
      p2 = fmaf(v2, v2, p2); p3 = fmaf(v3, v3, p3);
    }
    float s0 = 64.0f + (p0 + p1) + (p2 + p3);
    sqx[c][wl] = s0;
    float a = xr[wl + S], b = xr[wl];
    sqx[c][wl + 1] = s0 + a * a - b * b;
  }
  __syncthreads();  // xcop + sqx ready; NO barriers after this point

  const f32x4 z4 = {0.0f, 0.0f, 0.0f, 0.0f};
  f32x4 dsum[4][4];   // [ktile][wtile]
#pragma unroll
  for (int kt = 0; kt < 4; ++kt)
#pragma unroll
    for (int wt = 0; wt < 4; ++wt) dsum[kt][wt] = z4;

  const int r8 = col & 7;
  const int abase = wgrp * 64 + (col - r8) + quad * 8;  // multiple of 8 -> b128 aligned

  for (int c = 0; c < C; ++c) {
    // B fragments for this channel: single named buffer, statically indexed.
    // 8 coalesced dwordx4 from L1/L2; resident-wave TLP covers the latency.
    bf16x8 Bc[8];
#pragma unroll
    for (int i = 0; i < 8; ++i)
      Bc[i] = *(const bf16x8*)(bw + c * 8192 + i * 512);

    const unsigned short* xc = &xcop[c][r8][0];
#pragma unroll
    for (int wt = 0; wt < 4; ++wt) {
      // acc init = sqx (broadcast read, shared across the 4 k-tiles)
      f32x4 ai = *(const f32x4*)&sqx[c][wgrp * 64 + wt * 16 + quad * 4];
      // A fragments read ONCE, feed 4 k-tiles
      bf16x8 x0 = *(const bf16x8*)(xc + abase + wt * 16);
      bf16x8 x1 = *(const bf16x8*)(xc + abase + wt * 16 + 32);
      f32x4 a0 = __builtin_amdgcn_mfma_f32_16x16x32_bf16(x0, Bc[0], ai, 0, 0, 0);
      f32x4 a1 = __builtin_amdgcn_mfma_f32_16x16x32_bf16(x0, Bc[2], ai, 0, 0, 0);
      f32x4 a2 = __builtin_amdgcn_mfma_f32_16x16x32_bf16(x0, Bc[4], ai, 0, 0, 0);
      f32x4 a3 = __builtin_amdgcn_mfma_f32_16x16x32_bf16(x0, Bc[6], ai, 0, 0, 0);
      a0 = __builtin_amdgcn_mfma_f32_16x16x32_bf16(x1, Bc[1], a0, 0, 0, 0);
      a1 = __builtin_amdgcn_mfma_f32_16x16x32_bf16(x1, Bc[3], a1, 0, 0, 0);
      a2 = __builtin_amdgcn_mfma_f32_16x16x32_bf16(x1, Bc[5], a2, 0, 0, 0);
      a3 = __builtin_amdgcn_mfma_f32_16x16x32_bf16(x1, Bc[7], a3, 0, 0, 0);
#pragma unroll
      for (int i = 0; i < 4; ++i) {
        dsum[0][wt][i] += __builtin_amdgcn_sqrtf(fmaxf(a0[i], 0.0f));
        dsum[1][wt][i] += __builtin_amdgcn_sqrtf(fmaxf(a1[i], 0.0f));
        dsum[2][wt][i] += __builtin_amdgcn_sqrtf(fmaxf(a2[i], 0.0f));
        dsum[3][wt][i] += __builtin_amdgcn_sqrtf(fmaxf(a3[i], 0.0f));
      }
    }
  }

  // min over w (regs -> quad shuffles), one atomicMin per (k-tile, lane col)
  const float INF = __int_as_float(0x7F800000);
  const int wbase = w0 + wgrp * 64;
#pragma unroll
  for (int kt = 0; kt < 4; ++kt) {
    float mv = INF;
#pragma unroll
    for (int wt = 0; wt < 4; ++wt)
#pragma unroll
      for (int i = 0; i < 4; ++i) {
        int w = wbase + wt * 16 + quad * 4 + i;
        mv = (w < W) ? fminf(mv, dsum[kt][wt][i]) : mv;
      }
    mv = fminf(mv, __shfl_xor(mv, 16));
    mv = fminf(mv, __shfl_xor(mv, 32));
    if (quad == 0)
      atomicMin(&out[n * K + kgrp * 64 + kt * 16 + col], __float_as_int(mv));
  }
}

extern "C" void kernel_launch(void* const* d_in, const int* in_sizes, int n_in,
                              void* d_out, int out_size, void* d_ws, size_t ws_size,
                              hipStream_t stream) {
  const float* x = (const float*)d_in[0];    // (64, 8, 2048) fp32
  const float* sh = (const float*)d_in[1];   // (8, 128, 64) fp32
  float* out = (float*)d_out;                // (64, 1, 128) fp32
  unsigned short* shzB = (unsigned short*)d_ws;  // 128 KB bf16 B-frag layout (scaled -2)

  prep_kernel<<<256, 256, 0, stream>>>(sh, shzB, out);
  main_kernel<<<dim3(NTW, NB), 256, 0, stream>>>(x, shzB, (int*)out);
}

// Round 5
// 87.591 us; speedup vs baseline: 2.9981x; 1.0038x over previous
//
#include <hip/hip_runtime.h>
#include <hip/hip_bf16.h>
#include <math.h>

#define C 8
#define K 128
#define S 64
#define L 2048
#define NB 64
#define W (L - S + 1)   // 1985
#define TW 128
#define NTW 16
#define XCS 208         // xcop stride shorts: 104 dw = 8 banks mod 32 -> conflict-free b128
#define XFS 200         // fp32 x scratch stride (192 data + 8 zero pad)

typedef __attribute__((ext_vector_type(8))) short bf16x8;
typedef __attribute__((ext_vector_type(4))) float f32x4;

__device__ __forceinline__ unsigned short f2bf(float f) {
  unsigned int u = __float_as_uint(f);
  u += 0x7FFFu + ((u >> 16) & 1u);   // RNE
  return (unsigned short)(u >> 16);
}

// packed f32x2 -> bf16x2 (v_cvt_pk_bf16_f32 on gfx950)
__device__ __forceinline__ unsigned int pkbf(float a, float b) {
  __hip_bfloat162 h = __float22bfloat162_rn(make_float2(a, b));
  return *reinterpret_cast<unsigned int*>(&h);
}

// prep: z-normalize shapelets -> bf16 * (-2), B-fragment order grouped by
// CHANNEL (16 KB contiguous per c, both 64k halves inside); init out to +inf.
// sum(z^2) == S == 64 exactly (population z-norm) -> no per-k sqs needed.
__global__ __launch_bounds__(256) void prep_kernel(const float* __restrict__ sh,
                                                   unsigned short* __restrict__ shzB,
                                                   float* __restrict__ out) {
  int tid = blockIdx.x * 256 + threadIdx.x;
  if (tid < NB * K) out[tid] = __int_as_float(0x7F800000);
  int gid = blockIdx.x * 4 + (threadIdx.x >> 6);  // c*K + k
  int lane = threadIdx.x & 63;                    // = s
  float v = sh[(size_t)gid * S + lane];
  float s1 = v, s2 = v * v;
#pragma unroll
  for (int off = 32; off > 0; off >>= 1) {
    s1 += __shfl_down(s1, off);
    s2 += __shfl_down(s2, off);
  }
  s1 = __shfl(s1, 0);
  s2 = __shfl(s2, 0);
  float mu = s1 * (1.0f / S);
  float sd = sqrtf(fmaxf(s2 * (1.0f / S) - mu * mu, 0.0f));
  float z = (v - mu) / sd;
  int c = gid >> 7, k = gid & (K - 1), s = lane;
  // layout: [c][k>>6][((k>>4)&3)*2 + (s>>5)][lane'=((s>>3)&3)*16+(k&15)][s&7]
  int idx = c * 8192 + (k >> 6) * 4096 + ((((k >> 4) & 3) * 2) + (s >> 5)) * 512 +
            ((((s >> 3) & 3) * 16 + (k & 15)) * 8) + (s & 7);
  shzB[idx] = f2bf(-2.0f * z);   // bake the -2 of d2 = (sqx + 64) - 2*cross
}

// main: block = 128w x 128k, 256 threads = 4 waves, wave tile 64w x 64k.
// R4 post-mortem: three structurally different kernels (16-wave lockstep,
// 8-wave dbuf, 8-wave barrier-free) all pin at 42.5us with VALUBusy 48% and
// no pipe >50% — the shared binder is the per-channel SERIAL chain
// [loads -> waitcnt -> MFMA -> 1300cy pure-trans sqrt block].
// R5 = channel-granularity software pipeline: carry the previous channel's
// MFMA accumulators p[4][4] (statically indexed, unrolled — rule-#20 safe)
// across the rolled loop; body = {issue B loads, issue A/sqx ds_reads,
// trans-epilogue of p (no dep on the loads -> vm/lgkm waits hide under it),
// MFMA -> p}. Channel summation ORDER unchanged -> bit-identical outputs.
// No pragma-unroll on the channel loop (R3 lesson), no manual cross-iter
// load hoisting. Tripwire: WRITE_SIZE must stay ~1MB (no spill).
__global__ __launch_bounds__(256, 2) void main_kernel(const float* __restrict__ x,
                                                      const unsigned short* __restrict__ shzB,
                                                      int* __restrict__ out) {
  __shared__ __align__(16) unsigned short xcop[C][8][XCS]; // 26 KB: 8 shifted copies
  __shared__ __align__(16) float sqx[C][TW];               // 4 KB (pre-biased +64)
  __shared__ __align__(16) float xf[C][XFS];               // 6.4 KB fp32 x scratch

  const int t = threadIdx.x;
  const int lane = t & 63;
  const int wave = t >> 6;     // 0..3
  const int wgrp = wave & 1;   // w-offset 64
  const int kgrp = wave >> 1;  // 0..1 : k-offset 64*kgrp
  const int col = lane & 15;
  const int quad = lane >> 4;
  const int n = blockIdx.y;
  const int w0 = blockIdx.x * TW;
  const float* xn = x + (size_t)n * C * L;
  // this wave's B-fragment stream: 8 x 1KB contiguous chunks per channel
  const unsigned short* bw = shzB + kgrp * 4096 + lane * 8;

  // ---- stage fp32 x segment into xf (2 ch/wave, float4/lane) ----
  float* xfp = &xf[0][0];
#pragma unroll
  for (int cc = 0; cc < 2; ++cc) {
    const int c = wave * 2 + cc;
    const int e = lane * 4;
    float4 v; v.x = v.y = v.z = v.w = 0.0f;
    if (lane < 48) {
      int g = w0 + e;
      if (g + 3 < L) {
        v = *(const float4*)(xn + c * L + g);
      } else {  // last w-tile tail; feeds masked windows only
        v.x = (g + 0 < L) ? xn[c * L + g + 0] : 0.0f;
        v.y = (g + 1 < L) ? xn[c * L + g + 1] : 0.0f;
        v.z = (g + 2 < L) ? xn[c * L + g + 2] : 0.0f;
        v.w = (g + 3 < L) ? xn[c * L + g + 3] : 0.0f;
      }
    }
    if (lane < 50) *(float4*)&xfp[c * XFS + e] = v;   // lanes 48,49 zero-pad tail
  }
  __syncthreads();

  // ---- build 8 shifted bf16 copies (2 ch/wave; r=lane>>3; 12 dwords/lane/ch) ----
#pragma unroll
  for (int cc = 0; cc < 2; ++cc) {
    const int cb = wave * 2 + cc;
    const int rb = lane >> 3;         // 0..7
    const int c8 = lane & 7;
    const float* xr = xfp + cb * XFS;
#pragma unroll
    for (int j = 0; j < 12; ++j) {
      int i = (c8 + j * 8) * 2;       // 0..190 even
      *(unsigned int*)&xcop[cb][rb][i] = pkbf(xr[i + rb], xr[i + rb + 1]);
    }
  }
  // ---- sliding-window fp32 sqx (+64 bias = sum(z^2)): 2 ch/wave, 2 w/lane ----
#pragma unroll
  for (int cc = 0; cc < 2; ++cc) {
    const int c = wave * 2 + cc, wl = lane * 2;
    const float* xr = xfp + c * XFS;
    float p0 = 0.f, p1 = 0.f, p2 = 0.f, p3 = 0.f;
#pragma unroll
    for (int si = 0; si < S; si += 4) {
      float v0 = xr[wl + si], v1 = xr[wl + si + 1], v2 = xr[wl + si + 2], v3 = xr[wl + si + 3];
      p0 = fmaf(v0, v0, p0); p1 = fmaf(v1, v1, p1);
      p2 = fmaf(v2, v2, p2); p3 = fmaf(v3, v3, p3);
    }
    float s0 = 64.0f + (p0 + p1) + (p2 + p3);
    sqx[c][wl] = s0;
    float a = xr[wl + S], b = xr[wl];
    sqx[c][wl + 1] = s0 + a * a - b * b;
  }
  __syncthreads();  // xcop + sqx ready; NO barriers after this point

  const f32x4 z4 = {0.0f, 0.0f, 0.0f, 0.0f};
  f32x4 dsum[4][4];   // [ktile][wtile]
#pragma unroll
  for (int kt = 0; kt < 4; ++kt)
#pragma unroll
    for (int wt = 0; wt < 4; ++wt) dsum[kt][wt] = z4;

  const int r8 = col & 7;
  const int abase = wgrp * 64 + (col - r8) + quad * 8;  // multiple of 8 -> b128 aligned

  // pipelined accumulators: channel c-1's MFMA results, epilogued one
  // iteration later (static indices only — unrolled loops)
  f32x4 p[4][4];

  // ---- channel 0: loads + MFMA into p (no epilogue yet) ----
  {
    bf16x8 Bc[8];
#pragma unroll
    for (int i = 0; i < 8; ++i)
      Bc[i] = *(const bf16x8*)(bw + i * 512);
    const unsigned short* xc = &xcop[0][r8][0];
#pragma unroll
    for (int wt = 0; wt < 4; ++wt) {
      f32x4 ai = *(const f32x4*)&sqx[0][wgrp * 64 + wt * 16 + quad * 4];
      bf16x8 x0 = *(const bf16x8*)(xc + abase + wt * 16);
      bf16x8 x1 = *(const bf16x8*)(xc + abase + wt * 16 + 32);
      p[0][wt] = __builtin_amdgcn_mfma_f32_16x16x32_bf16(x0, Bc[0], ai, 0, 0, 0);
      p[1][wt] = __builtin_amdgcn_mfma_f32_16x16x32_bf16(x0, Bc[2], ai, 0, 0, 0);
      p[2][wt] = __builtin_amdgcn_mfma_f32_16x16x32_bf16(x0, Bc[4], ai, 0, 0, 0);
      p[3][wt] = __builtin_amdgcn_mfma_f32_16x16x32_bf16(x0, Bc[6], ai, 0, 0, 0);
      p[0][wt] = __builtin_amdgcn_mfma_f32_16x16x32_bf16(x1, Bc[1], p[0][wt], 0, 0, 0);
      p[1][wt] = __builtin_amdgcn_mfma_f32_16x16x32_bf16(x1, Bc[3], p[1][wt], 0, 0, 0);
      p[2][wt] = __builtin_amdgcn_mfma_f32_16x16x32_bf16(x1, Bc[5], p[2][wt], 0, 0, 0);
      p[3][wt] = __builtin_amdgcn_mfma_f32_16x16x32_bf16(x1, Bc[7], p[3][wt], 0, 0, 0);
    }
  }

  for (int c = 1; c < C; ++c) {
    // (1) issue this channel's B loads (VMEM latency target for hiding)
    bf16x8 Bc[8];
#pragma unroll
    for (int i = 0; i < 8; ++i)
      Bc[i] = *(const bf16x8*)(bw + c * 8192 + i * 512);

    // (2) issue this channel's A-frag + sqx ds_reads (LDS latency target)
    const unsigned short* xc = &xcop[c][r8][0];
    bf16x8 xa0[4], xa1[4];
    f32x4 aiv[4];
#pragma unroll
    for (int wt = 0; wt < 4; ++wt) {
      xa0[wt] = *(const bf16x8*)(xc + abase + wt * 16);
      xa1[wt] = *(const bf16x8*)(xc + abase + wt * 16 + 32);
      aiv[wt] = *(const f32x4*)&sqx[c][wgrp * 64 + wt * 16 + quad * 4];
    }

    // (3) trans epilogue of channel c-1: no dependence on the loads above,
    // so the compiler's vm/lgkm waits land after ~1300 cycles of sqrt work
#pragma unroll
    for (int wt = 0; wt < 4; ++wt)
#pragma unroll
      for (int i = 0; i < 4; ++i) {
        dsum[0][wt][i] += __builtin_amdgcn_sqrtf(fmaxf(p[0][wt][i], 0.0f));
        dsum[1][wt][i] += __builtin_amdgcn_sqrtf(fmaxf(p[1][wt][i], 0.0f));
        dsum[2][wt][i] += __builtin_amdgcn_sqrtf(fmaxf(p[2][wt][i], 0.0f));
        dsum[3][wt][i] += __builtin_amdgcn_sqrtf(fmaxf(p[3][wt][i], 0.0f));
      }

    // (4) MFMA for this channel -> p
#pragma unroll
    for (int wt = 0; wt < 4; ++wt) {
      p[0][wt] = __builtin_amdgcn_mfma_f32_16x16x32_bf16(xa0[wt], Bc[0], aiv[wt], 0, 0, 0);
      p[1][wt] = __builtin_amdgcn_mfma_f32_16x16x32_bf16(xa0[wt], Bc[2], aiv[wt], 0, 0, 0);
      p[2][wt] = __builtin_amdgcn_mfma_f32_16x16x32_bf16(xa0[wt], Bc[4], aiv[wt], 0, 0, 0);
      p[3][wt] = __builtin_amdgcn_mfma_f32_16x16x32_bf16(xa0[wt], Bc[6], aiv[wt], 0, 0, 0);
      p[0][wt] = __builtin_amdgcn_mfma_f32_16x16x32_bf16(xa1[wt], Bc[1], p[0][wt], 0, 0, 0);
      p[1][wt] = __builtin_amdgcn_mfma_f32_16x16x32_bf16(xa1[wt], Bc[3], p[1][wt], 0, 0, 0);
      p[2][wt] = __builtin_amdgcn_mfma_f32_16x16x32_bf16(xa1[wt], Bc[5], p[2][wt], 0, 0, 0);
      p[3][wt] = __builtin_amdgcn_mfma_f32_16x16x32_bf16(xa1[wt], Bc[7], p[3][wt], 0, 0, 0);
    }
  }

  // final epilogue: channel 7
#pragma unroll
  for (int wt = 0; wt < 4; ++wt)
#pragma unroll
    for (int i = 0; i < 4; ++i) {
      dsum[0][wt][i] += __builtin_amdgcn_sqrtf(fmaxf(p[0][wt][i], 0.0f));
      dsum[1][wt][i] += __builtin_amdgcn_sqrtf(fmaxf(p[1][wt][i], 0.0f));
      dsum[2][wt][i] += __builtin_amdgcn_sqrtf(fmaxf(p[2][wt][i], 0.0f));
      dsum[3][wt][i] += __builtin_amdgcn_sqrtf(fmaxf(p[3][wt][i], 0.0f));
    }

  // min over w (regs -> quad shuffles), one atomicMin per (k-tile, lane col)
  const float INF = __int_as_float(0x7F800000);
  const int wbase = w0 + wgrp * 64;
#pragma unroll
  for (int kt = 0; kt < 4; ++kt) {
    float mv = INF;
#pragma unroll
    for (int wt = 0; wt < 4; ++wt)
#pragma unroll
      for (int i = 0; i < 4; ++i) {
        int w = wbase + wt * 16 + quad * 4 + i;
        mv = (w < W) ? fminf(mv, dsum[kt][wt][i]) : mv;
      }
    mv = fminf(mv, __shfl_xor(mv, 16));
    mv = fminf(mv, __shfl_xor(mv, 32));
    if (quad == 0)
      atomicMin(&out[n * K + kgrp * 64 + kt * 16 + col], __float_as_int(mv));
  }
}

extern "C" void kernel_launch(void* const* d_in, const int* in_sizes, int n_in,
                              void* d_out, int out_size, void* d_ws, size_t ws_size,
                              hipStream_t stream) {
  const float* x = (const float*)d_in[0];    // (64, 8, 2048) fp32
  const float* sh = (const float*)d_in[1];   // (8, 128, 64) fp32
  float* out = (float*)d_out;                // (64, 1, 128) fp32
  unsigned short* shzB = (unsigned short*)d_ws;  // 128 KB bf16 B-frag layout (scaled -2)

  prep_kernel<<<256, 256, 0, stream>>>(sh, shzB, out);
  main_kernel<<<dim3(NTW, NB), 256, 0, stream>>>(x, shzB, (int*)out);
}

// Round 6
// 86.479 us; speedup vs baseline: 3.0366x; 1.0129x over previous
//
#include <hip/hip_runtime.h>
#include <hip/hip_bf16.h>
#include <math.h>

#define C 8
#define K 128
#define S 64
#define L 2048
#define NB 64
#define W (L - S + 1)   // 1985
#define TW 128
#define NTW 16
#define XCS 208         // xcop stride shorts: 104 dw = 8 banks mod 32 -> conflict-free b128
#define XFS 200         // fp32 x scratch stride (192 data + 8 zero pad)

typedef __attribute__((ext_vector_type(8))) short bf16x8;
typedef __attribute__((ext_vector_type(4))) float f32x4;

__device__ __forceinline__ unsigned short f2bf(float f) {
  unsigned int u = __float_as_uint(f);
  u += 0x7FFFu + ((u >> 16) & 1u);   // RNE
  return (unsigned short)(u >> 16);
}

// packed f32x2 -> bf16x2 (v_cvt_pk_bf16_f32 on gfx950)
__device__ __forceinline__ unsigned int pkbf(float a, float b) {
  __hip_bfloat162 h = __float22bfloat162_rn(make_float2(a, b));
  return *reinterpret_cast<unsigned int*>(&h);
}

// prep: z-normalize shapelets -> bf16 * (-2), B-fragment order grouped by
// CHANNEL (16 KB contiguous per c, both 64k halves inside); init out to +inf.
// sum(z^2) == S == 64 exactly (population z-norm) -> no per-k sqs needed.
__global__ __launch_bounds__(256) void prep_kernel(const float* __restrict__ sh,
                                                   unsigned short* __restrict__ shzB,
                                                   float* __restrict__ out) {
  int tid = blockIdx.x * 256 + threadIdx.x;
  if (tid < NB * K) out[tid] = __int_as_float(0x7F800000);
  int gid = blockIdx.x * 4 + (threadIdx.x >> 6);  // c*K + k
  int lane = threadIdx.x & 63;                    // = s
  float v = sh[(size_t)gid * S + lane];
  float s1 = v, s2 = v * v;
#pragma unroll
  for (int off = 32; off > 0; off >>= 1) {
    s1 += __shfl_down(s1, off);
    s2 += __shfl_down(s2, off);
  }
  s1 = __shfl(s1, 0);
  s2 = __shfl(s2, 0);
  float mu = s1 * (1.0f / S);
  float sd = sqrtf(fmaxf(s2 * (1.0f / S) - mu * mu, 0.0f));
  float z = (v - mu) / sd;
  int c = gid >> 7, k = gid & (K - 1), s = lane;
  // layout: [c][k>>6][((k>>4)&3)*2 + (s>>5)][lane'=((s>>3)&3)*16+(k&15)][s&7]
  int idx = c * 8192 + (k >> 6) * 4096 + ((((k >> 4) & 3) * 2) + (s >> 5)) * 512 +
            ((((s >> 3) & 3) * 16 + (k & 15)) * 8) + (s & 7);
  shzB[idx] = f2bf(-2.0f * z);   // bake the -2 of d2 = (sqx + 64) - 2*cross
}

// main: block = 128w x 128k, 256 threads = 4 waves, wave tile 64w x 64k.
// R5 post-mortem: FIVE structures all pin at 42.5us, pipes summing serially
// (VALU 48% + MFMA 15% + LDS + VMEM-wait ~= total). The invariant across all
// five: co-resident waves run IDENTICAL code over the SAME channel sequence ->
// phase-locked -> trans blocks serialize on the trans pipe, waits coincide,
// no cross-wave pipe overlap.
// R6 = PHASE STAGGER: each wave/block walks the channel ring from a different
// start: c = (cbase+ci)&7, cbase = (2*wave + bx + by)&7. All per-channel data
// (xcop, sqx, L2-resident B) is ready before the loop, so order is legal;
// dsum accumulation is commutative (rounding shift ~1e-5 << 1.69 threshold).
// Keeps R5's channel-granularity pipeline (p[4][4] static-indexed, rule-#20
// safe). Piggyback: fmaxf(x,0) -> fabsf(x): abs is a free v_sqrt input
// modifier (64 fewer VALU instrs per wave-channel; differs only where true
// d2 ~ 0 within bf16 noise, both clamps give ~0).
// Tripwire: WRITE_SIZE must stay ~1MB (no spill).
__global__ __launch_bounds__(256, 2) void main_kernel(const float* __restrict__ x,
                                                      const unsigned short* __restrict__ shzB,
                                                      int* __restrict__ out) {
  __shared__ __align__(16) unsigned short xcop[C][8][XCS]; // 26 KB: 8 shifted copies
  __shared__ __align__(16) float sqx[C][TW];               // 4 KB (pre-biased +64)
  __shared__ __align__(16) float xf[C][XFS];               // 6.4 KB fp32 x scratch

  const int t = threadIdx.x;
  const int lane = t & 63;
  const int wave = t >> 6;     // 0..3
  const int wgrp = wave & 1;   // w-offset 64
  const int kgrp = wave >> 1;  // 0..1 : k-offset 64*kgrp
  const int col = lane & 15;
  const int quad = lane >> 4;
  const int n = blockIdx.y;
  const int w0 = blockIdx.x * TW;
  const float* xn = x + (size_t)n * C * L;
  // this wave's B-fragment stream: 8 x 1KB contiguous chunks per channel
  const unsigned short* bw = shzB + kgrp * 4096 + lane * 8;
  // phase-stagger start channel: wave-uniform (SGPR), differs across waves
  // AND across co-resident blocks
  const int cbase = (2 * wave + blockIdx.x + blockIdx.y) & 7;

  // ---- stage fp32 x segment into xf (2 ch/wave, float4/lane) ----
  float* xfp = &xf[0][0];
#pragma unroll
  for (int cc = 0; cc < 2; ++cc) {
    const int c = wave * 2 + cc;
    const int e = lane * 4;
    float4 v; v.x = v.y = v.z = v.w = 0.0f;
    if (lane < 48) {
      int g = w0 + e;
      if (g + 3 < L) {
        v = *(const float4*)(xn + c * L + g);
      } else {  // last w-tile tail; feeds masked windows only
        v.x = (g + 0 < L) ? xn[c * L + g + 0] : 0.0f;
        v.y = (g + 1 < L) ? xn[c * L + g + 1] : 0.0f;
        v.z = (g + 2 < L) ? xn[c * L + g + 2] : 0.0f;
        v.w = (g + 3 < L) ? xn[c * L + g + 3] : 0.0f;
      }
    }
    if (lane < 50) *(float4*)&xfp[c * XFS + e] = v;   // lanes 48,49 zero-pad tail
  }
  __syncthreads();

  // ---- build 8 shifted bf16 copies (2 ch/wave; r=lane>>3; 12 dwords/lane/ch) ----
#pragma unroll
  for (int cc = 0; cc < 2; ++cc) {
    const int cb = wave * 2 + cc;
    const int rb = lane >> 3;         // 0..7
    const int c8 = lane & 7;
    const float* xr = xfp + cb * XFS;
#pragma unroll
    for (int j = 0; j < 12; ++j) {
      int i = (c8 + j * 8) * 2;       // 0..190 even
      *(unsigned int*)&xcop[cb][rb][i] = pkbf(xr[i + rb], xr[i + rb + 1]);
    }
  }
  // ---- sliding-window fp32 sqx (+64 bias = sum(z^2)): 2 ch/wave, 2 w/lane ----
#pragma unroll
  for (int cc = 0; cc < 2; ++cc) {
    const int c = wave * 2 + cc, wl = lane * 2;
    const float* xr = xfp + c * XFS;
    float p0 = 0.f, p1 = 0.f, p2 = 0.f, p3 = 0.f;
#pragma unroll
    for (int si = 0; si < S; si += 4) {
      float v0 = xr[wl + si], v1 = xr[wl + si + 1], v2 = xr[wl + si + 2], v3 = xr[wl + si + 3];
      p0 = fmaf(v0, v0, p0); p1 = fmaf(v1, v1, p1);
      p2 = fmaf(v2, v2, p2); p3 = fmaf(v3, v3, p3);
    }
    float s0 = 64.0f + (p0 + p1) + (p2 + p3);
    sqx[c][wl] = s0;
    float a = xr[wl + S], b = xr[wl];
    sqx[c][wl + 1] = s0 + a * a - b * b;
  }
  __syncthreads();  // xcop + sqx ready; NO barriers after this point

  const f32x4 z4 = {0.0f, 0.0f, 0.0f, 0.0f};
  f32x4 dsum[4][4];   // [ktile][wtile]
#pragma unroll
  for (int kt = 0; kt < 4; ++kt)
#pragma unroll
    for (int wt = 0; wt < 4; ++wt) dsum[kt][wt] = z4;

  const int r8 = col & 7;
  const int abase = wgrp * 64 + (col - r8) + quad * 8;  // multiple of 8 -> b128 aligned

  // pipelined accumulators: previous channel's MFMA results, epilogued one
  // iteration later (static indices only — unrolled loops)
  f32x4 p[4][4];

  // ---- first channel (c = cbase): loads + MFMA into p (no epilogue yet) ----
  {
    const int c0 = cbase;
    bf16x8 Bc[8];
#pragma unroll
    for (int i = 0; i < 8; ++i)
      Bc[i] = *(const bf16x8*)(bw + c0 * 8192 + i * 512);
    const unsigned short* xc = &xcop[c0][r8][0];
#pragma unroll
    for (int wt = 0; wt < 4; ++wt) {
      f32x4 ai = *(const f32x4*)&sqx[c0][wgrp * 64 + wt * 16 + quad * 4];
      bf16x8 x0 = *(const bf16x8*)(xc + abase + wt * 16);
      bf16x8 x1 = *(const bf16x8*)(xc + abase + wt * 16 + 32);
      p[0][wt] = __builtin_amdgcn_mfma_f32_16x16x32_bf16(x0, Bc[0], ai, 0, 0, 0);
      p[1][wt] = __builtin_amdgcn_mfma_f32_16x16x32_bf16(x0, Bc[2], ai, 0, 0, 0);
      p[2][wt] = __builtin_amdgcn_mfma_f32_16x16x32_bf16(x0, Bc[4], ai, 0, 0, 0);
      p[3][wt] = __builtin_amdgcn_mfma_f32_16x16x32_bf16(x0, Bc[6], ai, 0, 0, 0);
      p[0][wt] = __builtin_amdgcn_mfma_f32_16x16x32_bf16(x1, Bc[1], p[0][wt], 0, 0, 0);
      p[1][wt] = __builtin_amdgcn_mfma_f32_16x16x32_bf16(x1, Bc[3], p[1][wt], 0, 0, 0);
      p[2][wt] = __builtin_amdgcn_mfma_f32_16x16x32_bf16(x1, Bc[5], p[2][wt], 0, 0, 0);
      p[3][wt] = __builtin_amdgcn_mfma_f32_16x16x32_bf16(x1, Bc[7], p[3][wt], 0, 0, 0);
    }
  }

  for (int ci = 1; ci < C; ++ci) {
    const int c = (cbase + ci) & 7;   // wave-uniform (SGPR arithmetic)

    // (1) issue this channel's B loads (VMEM latency target for hiding)
    bf16x8 Bc[8];
#pragma unroll
    for (int i = 0; i < 8; ++i)
      Bc[i] = *(const bf16x8*)(bw + c * 8192 + i * 512);

    // (2) issue this channel's A-frag + sqx ds_reads (LDS latency target)
    const unsigned short* xc = &xcop[c][r8][0];
    bf16x8 xa0[4], xa1[4];
    f32x4 aiv[4];
#pragma unroll
    for (int wt = 0; wt < 4; ++wt) {
      xa0[wt] = *(const bf16x8*)(xc + abase + wt * 16);
      xa1[wt] = *(const bf16x8*)(xc + abase + wt * 16 + 32);
      aiv[wt] = *(const f32x4*)&sqx[c][wgrp * 64 + wt * 16 + quad * 4];
    }

    // (3) trans epilogue of the previous channel: no dependence on the loads
    // above, so the vm/lgkm waits hide under ~1000 cycles of sqrt work
#pragma unroll
    for (int wt = 0; wt < 4; ++wt)
#pragma unroll
      for (int i = 0; i < 4; ++i) {
        dsum[0][wt][i] += __builtin_amdgcn_sqrtf(__builtin_fabsf(p[0][wt][i]));
        dsum[1][wt][i] += __builtin_amdgcn_sqrtf(__builtin_fabsf(p[1][wt][i]));
        dsum[2][wt][i] += __builtin_amdgcn_sqrtf(__builtin_fabsf(p[2][wt][i]));
        dsum[3][wt][i] += __builtin_amdgcn_sqrtf(__builtin_fabsf(p[3][wt][i]));
      }

    // (4) MFMA for this channel -> p
#pragma unroll
    for (int wt = 0; wt < 4; ++wt) {
      p[0][wt] = __builtin_amdgcn_mfma_f32_16x16x32_bf16(xa0[wt], Bc[0], aiv[wt], 0, 0, 0);
      p[1][wt] = __builtin_amdgcn_mfma_f32_16x16x32_bf16(xa0[wt], Bc[2], aiv[wt], 0, 0, 0);
      p[2][wt] = __builtin_amdgcn_mfma_f32_16x16x32_bf16(xa0[wt], Bc[4], aiv[wt], 0, 0, 0);
      p[3][wt] = __builtin_amdgcn_mfma_f32_16x16x32_bf16(xa0[wt], Bc[6], aiv[wt], 0, 0, 0);
      p[0][wt] = __builtin_amdgcn_mfma_f32_16x16x32_bf16(xa1[wt], Bc[1], p[0][wt], 0, 0, 0);
      p[1][wt] = __builtin_amdgcn_mfma_f32_16x16x32_bf16(xa1[wt], Bc[3], p[1][wt], 0, 0, 0);
      p[2][wt] = __builtin_amdgcn_mfma_f32_16x16x32_bf16(xa1[wt], Bc[5], p[2][wt], 0, 0, 0);
      p[3][wt] = __builtin_amdgcn_mfma_f32_16x16x32_bf16(xa1[wt], Bc[7], p[3][wt], 0, 0, 0);
    }
  }

  // final epilogue: last channel in this wave's ring order
#pragma unroll
  for (int wt = 0; wt < 4; ++wt)
#pragma unroll
    for (int i = 0; i < 4; ++i) {
      dsum[0][wt][i] += __builtin_amdgcn_sqrtf(__builtin_fabsf(p[0][wt][i]));
      dsum[1][wt][i] += __builtin_amdgcn_sqrtf(__builtin_fabsf(p[1][wt][i]));
      dsum[2][wt][i] += __builtin_amdgcn_sqrtf(__builtin_fabsf(p[2][wt][i]));
      dsum[3][wt][i] += __builtin_amdgcn_sqrtf(__builtin_fabsf(p[3][wt][i]));
    }

  // min over w (regs -> quad shuffles), one atomicMin per (k-tile, lane col)
  const float INF = __int_as_float(0x7F800000);
  const int wbase = w0 + wgrp * 64;
#pragma unroll
  for (int kt = 0; kt < 4; ++kt) {
    float mv = INF;
#pragma unroll
    for (int wt = 0; wt < 4; ++wt)
#pragma unroll
      for (int i = 0; i < 4; ++i) {
        int w = wbase + wt * 16 + quad * 4 + i;
        mv = (w < W) ? fminf(mv, dsum[kt][wt][i]) : mv;
      }
    mv = fminf(mv, __shfl_xor(mv, 16));
    mv = fminf(mv, __shfl_xor(mv, 32));
    if (quad == 0)
      atomicMin(&out[n * K + kgrp * 64 + kt * 16 + col], __float_as_int(mv));
  }
}

extern "C" void kernel_launch(void* const* d_in, const int* in_sizes, int n_in,
                              void* d_out, int out_size, void* d_ws, size_t ws_size,
                              hipStream_t stream) {
  const float* x = (const float*)d_in[0];    // (64, 8, 2048) fp32
  const float* sh = (const float*)d_in[1];   // (8, 128, 64) fp32
  float* out = (float*)d_out;                // (64, 1, 128) fp32
  unsigned short* shzB = (unsigned short*)d_ws;  // 128 KB bf16 B-frag layout (scaled -2)

  prep_kernel<<<256, 256, 0, stream>>>(sh, shzB, out);
  main_kernel<<<dim3(NTW, NB), 256, 0, stream>>>(x, shzB, (int*)out);
}

// Round 7
// 81.406 us; speedup vs baseline: 3.2258x; 1.0623x over previous
//
#include <hip/hip_runtime.h>
#include <hip/hip_bf16.h>
#include <math.h>

#define C 8
#define K 128
#define S 64
#define L 2048
#define NB 64
#define W (L - S + 1)   // 1985
#define TW 128
#define NTW 16
#define XCS 208         // xcop stride shorts: 104 dw = 8 banks mod 32 -> conflict-free b128
#define XFS 200         // fp32 x scratch stride (192 data + 8 zero pad)

typedef __attribute__((ext_vector_type(8))) short bf16x8;
typedef __attribute__((ext_vector_type(4))) float f32x4;

__device__ __forceinline__ unsigned short f2bf(float f) {
  unsigned int u = __float_as_uint(f);
  u += 0x7FFFu + ((u >> 16) & 1u);   // RNE
  return (unsigned short)(u >> 16);
}

// packed f32x2 -> bf16x2 (v_cvt_pk_bf16_f32 on gfx950)
__device__ __forceinline__ unsigned int pkbf(float a, float b) {
  __hip_bfloat162 h = __float22bfloat162_rn(make_float2(a, b));
  return *reinterpret_cast<unsigned int*>(&h);
}

// prep: z-normalize shapelets -> bf16 * (-2), B-fragment order grouped by
// CHANNEL (16 KB contiguous per c, both 64k halves inside); init out to +inf.
// sum(z^2) == S == 64 exactly (population z-norm) -> no per-k sqs needed.
__global__ __launch_bounds__(256) void prep_kernel(const float* __restrict__ sh,
                                                   unsigned short* __restrict__ shzB,
                                                   float* __restrict__ out) {
  int tid = blockIdx.x * 256 + threadIdx.x;
  if (tid < NB * K) out[tid] = __int_as_float(0x7F800000);
  int gid = blockIdx.x * 4 + (threadIdx.x >> 6);  // c*K + k
  int lane = threadIdx.x & 63;                    // = s
  float v = sh[(size_t)gid * S + lane];
  float s1 = v, s2 = v * v;
#pragma unroll
  for (int off = 32; off > 0; off >>= 1) {
    s1 += __shfl_down(s1, off);
    s2 += __shfl_down(s2, off);
  }
  s1 = __shfl(s1, 0);
  s2 = __shfl(s2, 0);
  float mu = s1 * (1.0f / S);
  float sd = sqrtf(fmaxf(s2 * (1.0f / S) - mu * mu, 0.0f));
  float z = (v - mu) / sd;
  int c = gid >> 7, k = gid & (K - 1), s = lane;
  // layout: [c][k>>6][((k>>4)&3)*2 + (s>>5)][lane'=((s>>3)&3)*16+(k&15)][s&7]
  int idx = c * 8192 + (k >> 6) * 4096 + ((((k >> 4) & 3) * 2) + (s >> 5)) * 512 +
            ((((s >> 3) & 3) * 16 + (k & 15)) * 8) + (s & 7);
  shzB[idx] = f2bf(-2.0f * z);   // bake the -2 of d2 = (sqx + 64) - 2*cross
}

// One wt-subtile: 8 MFMAs (4 kt x 2 halves) into P[0..3] (all indices literal)
#define WT_COMPUTE(WT, P)                                                     \
  {                                                                           \
    bf16x8 x0 = *(const bf16x8*)(xc + abase + (WT) * 16);                     \
    bf16x8 x1 = *(const bf16x8*)(xc + abase + (WT) * 16 + 32);                \
    f32x4 ai = *(const f32x4*)&sqx[c][wgrp * 64 + (WT) * 16 + quad * 4];      \
    P[0] = __builtin_amdgcn_mfma_f32_16x16x32_bf16(x0, Bc[0], ai, 0, 0, 0);   \
    P[1] = __builtin_amdgcn_mfma_f32_16x16x32_bf16(x0, Bc[2], ai, 0, 0, 0);   \
    P[2] = __builtin_amdgcn_mfma_f32_16x16x32_bf16(x0, Bc[4], ai, 0, 0, 0);   \
    P[3] = __builtin_amdgcn_mfma_f32_16x16x32_bf16(x0, Bc[6], ai, 0, 0, 0);   \
    P[0] = __builtin_amdgcn_mfma_f32_16x16x32_bf16(x1, Bc[1], P[0], 0, 0, 0); \
    P[1] = __builtin_amdgcn_mfma_f32_16x16x32_bf16(x1, Bc[3], P[1], 0, 0, 0); \
    P[2] = __builtin_amdgcn_mfma_f32_16x16x32_bf16(x1, Bc[5], P[2], 0, 0, 0); \
    P[3] = __builtin_amdgcn_mfma_f32_16x16x32_bf16(x1, Bc[7], P[3], 0, 0, 0); \
  }

// trans epilogue of one wt-subtile (literal WT -> static dsum indexing)
#define WT_SQRT(WT, P)                                                        \
  {                                                                           \
    _Pragma("unroll")                                                         \
    for (int i = 0; i < 4; ++i) {                                             \
      dsum[0][WT][i] += __builtin_amdgcn_sqrtf(__builtin_fabsf(P[0][i]));     \
      dsum[1][WT][i] += __builtin_amdgcn_sqrtf(__builtin_fabsf(P[1][i]));     \
      dsum[2][WT][i] += __builtin_amdgcn_sqrtf(__builtin_fabsf(P[2][i]));     \
      dsum[3][WT][i] += __builtin_amdgcn_sqrtf(__builtin_fabsf(P[3][i]));     \
    }                                                                         \
  }

// main: block = 128w x 128k, 256 threads = 4 waves, wave tile 64w x 64k.
// R6 post-mortem: with v_sqrt_f32 ~16cyc/wave64, VALUBusy 48% is exactly
// [4 waves/SIMD of work x (8.2K trans + ~4K other)] / 100K cycles — the
// kernel is trans-work dominated and the trans pipe is only half fed,
// because register state (dsum 64 + p 64 + Bc 32 + hoists 48 ~ 200 regs)
// caps residency at 2 waves/SIMD. Device sqrt floor ~ 13.5 us.
// R7 = HALVE THE LIVE STATE at the same tile: replace the channel-level
// pipeline with wt-granularity alternation (pA/pB, 32 regs): compute wt0,
// compute wt1, sqrt wt0, compute wt2, sqrt wt1, compute wt3, sqrt wt2,
// sqrt wt3. MFMA->sqrt latency still covered; all names/indices static
// (rule-#20 safe). Keep R6's channel stagger + fabs-as-modifier.
// launch_bounds(256,3): cap ~170 VGPR (no spill) -> 3 waves/SIMD resident.
// Tripwire: WRITE_SIZE must stay ~1MB (no spill).
__global__ __launch_bounds__(256, 3) void main_kernel(const float* __restrict__ x,
                                                      const unsigned short* __restrict__ shzB,
                                                      int* __restrict__ out) {
  __shared__ __align__(16) unsigned short xcop[C][8][XCS]; // 26 KB: 8 shifted copies
  __shared__ __align__(16) float sqx[C][TW];               // 4 KB (pre-biased +64)
  __shared__ __align__(16) float xf[C][XFS];               // 6.4 KB fp32 x scratch

  const int t = threadIdx.x;
  const int lane = t & 63;
  const int wave = t >> 6;     // 0..3
  const int wgrp = wave & 1;   // w-offset 64
  const int kgrp = wave >> 1;  // 0..1 : k-offset 64*kgrp
  const int col = lane & 15;
  const int quad = lane >> 4;
  const int n = blockIdx.y;
  const int w0 = blockIdx.x * TW;
  const float* xn = x + (size_t)n * C * L;
  // this wave's B-fragment stream: 8 x 1KB contiguous chunks per channel
  const unsigned short* bw = shzB + kgrp * 4096 + lane * 8;
  // phase-stagger start channel (wave-uniform SGPR; decorrelates waves/blocks)
  const int cbase = (2 * wave + blockIdx.x + blockIdx.y) & 7;

  // ---- stage fp32 x segment into xf (2 ch/wave, float4/lane) ----
  float* xfp = &xf[0][0];
#pragma unroll
  for (int cc = 0; cc < 2; ++cc) {
    const int c = wave * 2 + cc;
    const int e = lane * 4;
    float4 v; v.x = v.y = v.z = v.w = 0.0f;
    if (lane < 48) {
      int g = w0 + e;
      if (g + 3 < L) {
        v = *(const float4*)(xn + c * L + g);
      } else {  // last w-tile tail; feeds masked windows only
        v.x = (g + 0 < L) ? xn[c * L + g + 0] : 0.0f;
        v.y = (g + 1 < L) ? xn[c * L + g + 1] : 0.0f;
        v.z = (g + 2 < L) ? xn[c * L + g + 2] : 0.0f;
        v.w = (g + 3 < L) ? xn[c * L + g + 3] : 0.0f;
      }
    }
    if (lane < 50) *(float4*)&xfp[c * XFS + e] = v;   // lanes 48,49 zero-pad tail
  }
  __syncthreads();

  // ---- build 8 shifted bf16 copies (2 ch/wave; r=lane>>3; 12 dwords/lane/ch) ----
#pragma unroll
  for (int cc = 0; cc < 2; ++cc) {
    const int cb = wave * 2 + cc;
    const int rb = lane >> 3;         // 0..7
    const int c8 = lane & 7;
    const float* xr = xfp + cb * XFS;
#pragma unroll
    for (int j = 0; j < 12; ++j) {
      int i = (c8 + j * 8) * 2;       // 0..190 even
      *(unsigned int*)&xcop[cb][rb][i] = pkbf(xr[i + rb], xr[i + rb + 1]);
    }
  }
  // ---- sliding-window fp32 sqx (+64 bias = sum(z^2)): 2 ch/wave, 2 w/lane ----
#pragma unroll
  for (int cc = 0; cc < 2; ++cc) {
    const int c = wave * 2 + cc, wl = lane * 2;
    const float* xr = xfp + c * XFS;
    float p0 = 0.f, p1 = 0.f, p2 = 0.f, p3 = 0.f;
#pragma unroll
    for (int si = 0; si < S; si += 4) {
      float v0 = xr[wl + si], v1 = xr[wl + si + 1], v2 = xr[wl + si + 2], v3 = xr[wl + si + 3];
      p0 = fmaf(v0, v0, p0); p1 = fmaf(v1, v1, p1);
      p2 = fmaf(v2, v2, p2); p3 = fmaf(v3, v3, p3);
    }
    float s0 = 64.0f + (p0 + p1) + (p2 + p3);
    sqx[c][wl] = s0;
    float a = xr[wl + S], b = xr[wl];
    sqx[c][wl + 1] = s0 + a * a - b * b;
  }
  __syncthreads();  // xcop + sqx ready; NO barriers after this point

  const f32x4 z4 = {0.0f, 0.0f, 0.0f, 0.0f};
  f32x4 dsum[4][4];   // [ktile][wtile]
#pragma unroll
  for (int kt = 0; kt < 4; ++kt)
#pragma unroll
    for (int wt = 0; wt < 4; ++wt) dsum[kt][wt] = z4;

  const int r8 = col & 7;
  const int abase = wgrp * 64 + (col - r8) + quad * 8;  // multiple of 8 -> b128 aligned

  for (int ci = 0; ci < C; ++ci) {
    const int c = (cbase + ci) & 7;   // wave-uniform (SGPR arithmetic)

    // B fragments for this channel: 8 coalesced dwordx4 from L1/L2
    bf16x8 Bc[8];
#pragma unroll
    for (int i = 0; i < 8; ++i)
      Bc[i] = *(const bf16x8*)(bw + c * 8192 + i * 512);

    const unsigned short* xc = &xcop[c][r8][0];

    // wt-granularity alternation: MFMA(wt+1) drains while sqrt(wt) runs.
    // Only 32 regs of accumulator-in-flight state (vs 64 channel-level).
    f32x4 pA[4], pB[4];
    WT_COMPUTE(0, pA)
    WT_COMPUTE(1, pB)
    WT_SQRT(0, pA)
    WT_COMPUTE(2, pA)
    WT_SQRT(1, pB)
    WT_COMPUTE(3, pB)
    WT_SQRT(2, pA)
    WT_SQRT(3, pB)
  }

  // min over w (regs -> quad shuffles), one atomicMin per (k-tile, lane col)
  const float INF = __int_as_float(0x7F800000);
  const int wbase = w0 + wgrp * 64;
#pragma unroll
  for (int kt = 0; kt < 4; ++kt) {
    float mv = INF;
#pragma unroll
    for (int wt = 0; wt < 4; ++wt)
#pragma unroll
      for (int i = 0; i < 4; ++i) {
        int w = wbase + wt * 16 + quad * 4 + i;
        mv = (w < W) ? fminf(mv, dsum[kt][wt][i]) : mv;
      }
    mv = fminf(mv, __shfl_xor(mv, 16));
    mv = fminf(mv, __shfl_xor(mv, 32));
    if (quad == 0)
      atomicMin(&out[n * K + kgrp * 64 + kt * 16 + col], __float_as_int(mv));
  }
}

extern "C" void kernel_launch(void* const* d_in, const int* in_sizes, int n_in,
                              void* d_out, int out_size, void* d_ws, size_t ws_size,
                              hipStream_t stream) {
  const float* x = (const float*)d_in[0];    // (64, 8, 2048) fp32
  const float* sh = (const float*)d_in[1];   // (8, 128, 64) fp32
  float* out = (float*)d_out;                // (64, 1, 128) fp32
  unsigned short* shzB = (unsigned short*)d_ws;  // 128 KB bf16 B-frag layout (scaled -2)

  prep_kernel<<<256, 256, 0, stream>>>(sh, shzB, out);
  main_kernel<<<dim3(NTW, NB), 256, 0, stream>>>(x, shzB, (int*)out);
}